// Round 1
// baseline (310.531 us; speedup 1.0000x reference)
//
#include <hip/hip_runtime.h>

// NodeClassifier: 3-layer message-passing GNN on MI355X.
// Strategy: transform-then-gather (h = x@W+b via tiled f32 GEMM), then
// CSR-based aggregation (counting sort of edges by dst each call — no fp32
// atomics in the hot aggregation, single coalesced write per output element).

#define N_NODES   10000
#define N_EDGES   320000
#define D_IN      256
#define D_HID     256
#define N_CLASSES 40

// ---------------- CSR build ----------------

__global__ void hist_kernel(const int* __restrict__ dst, int* __restrict__ deg) {
    int e = blockIdx.x * blockDim.x + threadIdx.x;
    if (e < N_EDGES) atomicAdd(&deg[dst[e]], 1);
}

__global__ void scan_kernel(const int* __restrict__ deg, int* __restrict__ starts) {
    __shared__ int sums[256];
    const int CH = (N_NODES + 255) / 256;  // 40
    int tid = threadIdx.x;
    int base = tid * CH;
    int s = 0;
    for (int i = 0; i < CH; ++i) {
        int idx = base + i;
        if (idx < N_NODES) s += deg[idx];
    }
    sums[tid] = s;
    __syncthreads();
    // Hillis-Steele inclusive scan over 256 partials
    for (int off = 1; off < 256; off <<= 1) {
        int v = (tid >= off) ? sums[tid - off] : 0;
        __syncthreads();
        sums[tid] += v;
        __syncthreads();
    }
    int run = (tid == 0) ? 0 : sums[tid - 1];
    for (int i = 0; i < CH; ++i) {
        int idx = base + i;
        if (idx < N_NODES) { starts[idx] = run; run += deg[idx]; }
    }
}

__global__ void place_kernel(const int* __restrict__ src, const int* __restrict__ dst,
                             const int* __restrict__ starts, int* __restrict__ cursor,
                             int* __restrict__ esrc) {
    int e = blockIdx.x * blockDim.x + threadIdx.x;
    if (e < N_EDGES) {
        int d = dst[e];
        int pos = starts[d] + atomicAdd(&cursor[d], 1);
        esrc[pos] = src[e];
    }
}

// ---------------- GEMM: C = A(MxK) * B(KxN) + bias ----------------
// BM=64, BN=64, BK=16, 256 threads, 4x4 per thread.

#define BM 64
#define BN 64
#define BK 16

__global__ void gemm_bias_kernel(const float* __restrict__ A, const float* __restrict__ B,
                                 const float* __restrict__ bias, float* __restrict__ C,
                                 int M, int N, int K) {
    __shared__ float As[BK][BM + 4];  // +4 keeps float4 alignment, breaks pow2 stride
    __shared__ float Bs[BK][BN + 4];
    const int tid = threadIdx.x;
    const int tx = tid & 15;
    const int ty = tid >> 4;
    const int rowBase = blockIdx.x * BM;
    const int colBase = blockIdx.y * BN;
    float acc[4][4] = {};

    for (int k0 = 0; k0 < K; k0 += BK) {
        // A tile: BM x BK, float4 along K, store transposed As[k][m]
        {
            int m  = tid >> 2;
            int kq = (tid & 3) << 2;
            int row = rowBase + m;
            float4 v = make_float4(0.f, 0.f, 0.f, 0.f);
            if (row < M) v = *(const float4*)(A + (size_t)row * K + k0 + kq);
            As[kq + 0][m] = v.x;
            As[kq + 1][m] = v.y;
            As[kq + 2][m] = v.z;
            As[kq + 3][m] = v.w;
        }
        // B tile: BK x BN, float4 along N
        {
            int kk = tid >> 4;
            int cq = (tid & 15) << 2;
            int col = colBase + cq;
            float4 v = make_float4(0.f, 0.f, 0.f, 0.f);
            const float* brow = B + (size_t)(k0 + kk) * N;
            if (col + 3 < N) {
                v = *(const float4*)(brow + col);
            } else if (col < N) {
                v.x = brow[col];
                if (col + 1 < N) v.y = brow[col + 1];
                if (col + 2 < N) v.z = brow[col + 2];
            }
            *(float4*)&Bs[kk][cq] = v;
        }
        __syncthreads();
#pragma unroll
        for (int kk = 0; kk < BK; ++kk) {
            float4 av = *(const float4*)&As[kk][ty << 2];
            float4 bv = *(const float4*)&Bs[kk][tx << 2];
            float a[4] = {av.x, av.y, av.z, av.w};
            float b[4] = {bv.x, bv.y, bv.z, bv.w};
#pragma unroll
            for (int i = 0; i < 4; ++i)
#pragma unroll
                for (int j = 0; j < 4; ++j)
                    acc[i][j] = fmaf(a[i], b[j], acc[i][j]);
        }
        __syncthreads();
    }

    int col = colBase + (tx << 2);
    if (col + 3 < N) {  // N is a multiple of 4 here (256 or 40): all-or-nothing
        float4 bv = *(const float4*)(bias + col);
#pragma unroll
        for (int i = 0; i < 4; ++i) {
            int row = rowBase + (ty << 2) + i;
            if (row < M) {
                float4 o;
                o.x = acc[i][0] + bv.x;
                o.y = acc[i][1] + bv.y;
                o.z = acc[i][2] + bv.z;
                o.w = acc[i][3] + bv.w;
                *(float4*)(C + (size_t)row * N + col) = o;
            }
        }
    }
}

// ---------------- Aggregation: out[n] = relu(sum_{e: dst=n} h[src_e]) ----------------
// One wave per node; 256 channels = float4 per lane.

__global__ void agg_relu_256_kernel(const float* __restrict__ h, const int* __restrict__ starts,
                                    const int* __restrict__ deg, const int* __restrict__ esrc,
                                    float* __restrict__ out) {
    int wv   = threadIdx.x >> 6;
    int lane = threadIdx.x & 63;
    int node = (blockIdx.x << 2) + wv;
    if (node >= N_NODES) return;
    int s0  = starts[node];
    int cnt = deg[node];
    const float4* hp = (const float4*)h;
    float4 acc = make_float4(0.f, 0.f, 0.f, 0.f);
    int i = 0;
    for (; i + 1 < cnt; i += 2) {
        int sa = esrc[s0 + i];
        int sb = esrc[s0 + i + 1];
        float4 va = hp[(size_t)sa * 64 + lane];
        float4 vb = hp[(size_t)sb * 64 + lane];
        acc.x += va.x + vb.x;
        acc.y += va.y + vb.y;
        acc.z += va.z + vb.z;
        acc.w += va.w + vb.w;
    }
    if (i < cnt) {
        int sa = esrc[s0 + i];
        float4 va = hp[(size_t)sa * 64 + lane];
        acc.x += va.x; acc.y += va.y; acc.z += va.z; acc.w += va.w;
    }
    float4 r;
    r.x = fmaxf(acc.x, 0.f);
    r.y = fmaxf(acc.y, 0.f);
    r.z = fmaxf(acc.z, 0.f);
    r.w = fmaxf(acc.w, 0.f);
    ((float4*)out)[(size_t)node * 64 + lane] = r;
}

__global__ void agg_relu_40_kernel(const float* __restrict__ h, const int* __restrict__ starts,
                                   const int* __restrict__ deg, const int* __restrict__ esrc,
                                   float* __restrict__ out) {
    int wv   = threadIdx.x >> 6;
    int lane = threadIdx.x & 63;
    int node = (blockIdx.x << 2) + wv;
    if (node >= N_NODES) return;
    int s0  = starts[node];
    int cnt = deg[node];
    if (lane < N_CLASSES) {
        float acc = 0.f;
        for (int i = 0; i < cnt; ++i) {
            int s = esrc[s0 + i];
            acc += h[(size_t)s * N_CLASSES + lane];
        }
        out[(size_t)node * N_CLASSES + lane] = fmaxf(acc, 0.f);
    }
}

// ---------------- launch ----------------

extern "C" void kernel_launch(void* const* d_in, const int* in_sizes, int n_in,
                              void* d_out, int out_size, void* d_ws, size_t ws_size,
                              hipStream_t stream) {
    const float* X     = (const float*)d_in[0];
    const int*   edges = (const int*)d_in[1];   // [2, E] int32 (JAX canonicalizes int64)
    const float* W1 = (const float*)d_in[2];
    const float* b1 = (const float*)d_in[3];
    const float* W2 = (const float*)d_in[4];
    const float* b2 = (const float*)d_in[5];
    const float* W3 = (const float*)d_in[6];
    const float* b3 = (const float*)d_in[7];
    float* out = (float*)d_out;

    char* ws = (char*)d_ws;
    float* bufA  = (float*)(ws);                 // 10,240,000 B  (h1/h2/h3)
    float* bufB  = (float*)(ws + 10240000);      // 10,240,000 B  (x1/x2)
    int*   deg   = (int*)(ws + 20480000);        // 40,000 B
    int*   cursor= (int*)(ws + 20520000);        // 40,000 B
    int*   starts= (int*)(ws + 20560000);        // 40,000 B
    int*   esrc  = (int*)(ws + 20600000);        // 1,280,000 B

    const int* srcp = edges;
    const int* dstp = edges + N_EDGES;

    // zero deg + cursor (contiguous 80 KB)
    hipMemsetAsync(deg, 0, 80000, stream);

    hist_kernel<<<(N_EDGES + 255) / 256, 256, 0, stream>>>(dstp, deg);
    scan_kernel<<<1, 256, 0, stream>>>(deg, starts);
    place_kernel<<<(N_EDGES + 255) / 256, 256, 0, stream>>>(srcp, dstp, starts, cursor, esrc);

    dim3 gridMM((N_NODES + BM - 1) / BM, (D_HID + BN - 1) / BN);       // 157 x 4
    dim3 gridM3((N_NODES + BM - 1) / BM, (N_CLASSES + BN - 1) / BN);   // 157 x 1

    // Layer 1
    gemm_bias_kernel<<<gridMM, 256, 0, stream>>>(X, W1, b1, bufA, N_NODES, D_HID, D_IN);
    agg_relu_256_kernel<<<(N_NODES + 3) / 4, 256, 0, stream>>>(bufA, starts, deg, esrc, bufB);
    // Layer 2
    gemm_bias_kernel<<<gridMM, 256, 0, stream>>>(bufB, W2, b2, bufA, N_NODES, D_HID, D_HID);
    agg_relu_256_kernel<<<(N_NODES + 3) / 4, 256, 0, stream>>>(bufA, starts, deg, esrc, bufB);
    // Layer 3
    gemm_bias_kernel<<<gridM3, 256, 0, stream>>>(bufB, W3, b3, bufA, N_NODES, N_CLASSES, D_HID);
    agg_relu_40_kernel<<<(N_NODES + 3) / 4, 256, 0, stream>>>(bufA, starts, deg, esrc, out);
}

// Round 2
// 258.927 us; speedup vs baseline: 1.1993x; 1.1993x over previous
//
#include <hip/hip_runtime.h>
#include <hip/hip_bf16.h>

// NodeClassifier: 3-layer message-passing GNN on MI355X.
// R2: bf16 MFMA GEMM (16x16x32), bf16 activations/h to halve gather traffic.
// CSR by counting sort each call (no fp32 atomics in aggregation).

#define N_NODES   10000
#define N_EDGES   320000
#define D_HID     256
#define N_CLASSES 40

typedef __attribute__((ext_vector_type(8))) short short8;
typedef __attribute__((ext_vector_type(4))) float f32x4;

__device__ __forceinline__ ushort f2bf(float f) {
    unsigned u = __float_as_uint(f);
    u = (u + 0x7fffu + ((u >> 16) & 1u)) >> 16;   // RNE; inputs finite
    return (ushort)u;
}
__device__ __forceinline__ float bf2f(ushort u) {
    return __uint_as_float(((unsigned)u) << 16);
}

// ---------------- CSR build ----------------

__global__ void hist_kernel(const int* __restrict__ dst, int* __restrict__ deg) {
    int e = blockIdx.x * blockDim.x + threadIdx.x;
    if (e < N_EDGES) atomicAdd(&deg[dst[e]], 1);
}

__global__ void scan_kernel(const int* __restrict__ deg, int* __restrict__ starts) {
    __shared__ int sums[256];
    const int CH = (N_NODES + 255) / 256;  // 40
    int tid = threadIdx.x;
    int base = tid * CH;
    int s = 0;
    for (int i = 0; i < CH; ++i) {
        int idx = base + i;
        if (idx < N_NODES) s += deg[idx];
    }
    sums[tid] = s;
    __syncthreads();
    for (int off = 1; off < 256; off <<= 1) {
        int v = (tid >= off) ? sums[tid - off] : 0;
        __syncthreads();
        sums[tid] += v;
        __syncthreads();
    }
    int run = (tid == 0) ? 0 : sums[tid - 1];
    for (int i = 0; i < CH; ++i) {
        int idx = base + i;
        if (idx < N_NODES) { starts[idx] = run; run += deg[idx]; }
    }
}

__global__ void place_kernel(const int* __restrict__ src, const int* __restrict__ dst,
                             const int* __restrict__ starts, int* __restrict__ cursor,
                             int* __restrict__ esrc) {
    int e = blockIdx.x * blockDim.x + threadIdx.x;
    if (e < N_EDGES) {
        int d = dst[e];
        int pos = starts[d] + atomicAdd(&cursor[d], 1);
        esrc[pos] = src[e];
    }
}

// ---------------- f32 -> bf16 conversions ----------------

// X: 10000x256 f32 -> bf16, float4 -> ushort4
__global__ void conv_x_kernel(const float* __restrict__ X, ushort* __restrict__ Xb) {
    int id = blockIdx.x * blockDim.x + threadIdx.x;   // 640000 float4s
    if (id < N_NODES * D_HID / 4) {
        float4 v = ((const float4*)X)[id];
        ushort4 o;
        o.x = f2bf(v.x); o.y = f2bf(v.y); o.z = f2bf(v.z); o.w = f2bf(v.w);
        ((ushort4*)Xb)[id] = o;
    }
}

// Weights: W[k][n] (K=256 x N) -> Wb[n][k] bf16 (transposed for MFMA B-operand)
__global__ void conv_w_kernel(const float* __restrict__ W1, const float* __restrict__ W2,
                              const float* __restrict__ W3,
                              ushort* __restrict__ W1b, ushort* __restrict__ W2b,
                              ushort* __restrict__ W3b) {
    int id = blockIdx.x * blockDim.x + threadIdx.x;
    if (id < 65536) {
        int n = id >> 8, k = id & 255;
        W1b[id] = f2bf(W1[k * 256 + n]);
    } else if (id < 131072) {
        int t = id - 65536;
        int n = t >> 8, k = t & 255;
        W2b[t] = f2bf(W2[k * 256 + n]);
    } else if (id < 141312) {
        int t = id - 131072;
        int n = t >> 8, k = t & 255;
        W3b[t] = f2bf(W3[k * N_CLASSES + n]);
    }
}

// ---------------- MFMA GEMM: C(bf16) = A(M x 256, bf16) * B^T(N x 256, bf16) + bias ----------------
// Tile 128x64, BK=32, 256 threads = 4 waves; wave w does rows [w*32, w*32+32).
#define LDA 40   // padded LDS row stride (bf16 elems): 2-way bank aliasing only (free)

__global__ __launch_bounds__(256)
void gemm_mfma_kernel(const ushort* __restrict__ A, const ushort* __restrict__ Bt,
                      const float* __restrict__ bias, ushort* __restrict__ C,
                      int M, int N) {
    __shared__ ushort As[128 * LDA];
    __shared__ ushort Bs[64 * LDA];
    const int tid = threadIdx.x;
    const int wave = tid >> 6, lane = tid & 63;
    const int lr = lane & 15, lg = lane >> 4;
    const int rowBase = blockIdx.x * 128;
    const int colBase = blockIdx.y * 64;
    f32x4 acc[2][4] = {};

    for (int k0 = 0; k0 < 256; k0 += 32) {
        // stage A: 128 rows x 32 k (16B chunks, 2 per thread)
#pragma unroll
        for (int rep = 0; rep < 2; ++rep) {
            int idx = rep * 256 + tid;
            int r = idx >> 2, c = (idx & 3) * 8;
            int grow = rowBase + r;
            uint4 v = make_uint4(0, 0, 0, 0);
            if (grow < M) v = *(const uint4*)(A + (size_t)grow * 256 + k0 + c);
            *(uint4*)(As + r * LDA + c) = v;
        }
        // stage B: 64 rows (n) x 32 k
        {
            int r = tid >> 2, c = (tid & 3) * 8;
            int gn = colBase + r;
            uint4 v = make_uint4(0, 0, 0, 0);
            if (gn < N) v = *(const uint4*)(Bt + (size_t)gn * 256 + k0 + c);
            *(uint4*)(Bs + r * LDA + c) = v;
        }
        __syncthreads();

        short8 af[2], bf[4];
#pragma unroll
        for (int t = 0; t < 2; ++t) {
            int m = wave * 32 + t * 16 + lr;
            af[t] = *(const short8*)(As + m * LDA + lg * 8);
        }
#pragma unroll
        for (int j = 0; j < 4; ++j) {
            int n = j * 16 + lr;
            bf[j] = *(const short8*)(Bs + n * LDA + lg * 8);
        }
#pragma unroll
        for (int t = 0; t < 2; ++t)
#pragma unroll
            for (int j = 0; j < 4; ++j)
                acc[t][j] = __builtin_amdgcn_mfma_f32_16x16x32_bf16(af[t], bf[j], acc[t][j], 0, 0, 0);
        __syncthreads();
    }

    // epilogue: D[row=lg*4+r][col=lr] per 16x16 tile; add bias, round to bf16
#pragma unroll
    for (int t = 0; t < 2; ++t) {
        int growBase = rowBase + wave * 32 + t * 16 + lg * 4;
#pragma unroll
        for (int j = 0; j < 4; ++j) {
            int col = colBase + j * 16 + lr;
            if (col < N) {
                float bv = bias[col];
#pragma unroll
                for (int r = 0; r < 4; ++r) {
                    int grow = growBase + r;
                    if (grow < M) C[(size_t)grow * N + col] = f2bf(acc[t][j][r] + bv);
                }
            }
        }
    }
}

// ---------------- Aggregation ----------------
// 256-dim: one wave per node, lane holds 4 bf16 channels (8B); f32 accumulate,
// relu, write bf16 (input of next layer's GEMM).
__global__ void agg_relu_256_kernel(const ushort* __restrict__ h, const int* __restrict__ starts,
                                    const int* __restrict__ deg, const int* __restrict__ esrc,
                                    ushort* __restrict__ out) {
    int wv   = threadIdx.x >> 6;
    int lane = threadIdx.x & 63;
    int node = (blockIdx.x << 2) + wv;
    if (node >= N_NODES) return;
    int s0  = starts[node];
    int cnt = deg[node];
    const uint2* hp = (const uint2*)h;
    float a0 = 0.f, a1 = 0.f, a2 = 0.f, a3 = 0.f;
    int i = 0;
    for (; i + 1 < cnt; i += 2) {
        int sa = esrc[s0 + i];
        int sb = esrc[s0 + i + 1];
        uint2 va = hp[(size_t)sa * 64 + lane];
        uint2 vb = hp[(size_t)sb * 64 + lane];
        a0 += bf2f((ushort)(va.x & 0xffff)) + bf2f((ushort)(vb.x & 0xffff));
        a1 += bf2f((ushort)(va.x >> 16))    + bf2f((ushort)(vb.x >> 16));
        a2 += bf2f((ushort)(va.y & 0xffff)) + bf2f((ushort)(vb.y & 0xffff));
        a3 += bf2f((ushort)(va.y >> 16))    + bf2f((ushort)(vb.y >> 16));
    }
    if (i < cnt) {
        int sa = esrc[s0 + i];
        uint2 va = hp[(size_t)sa * 64 + lane];
        a0 += bf2f((ushort)(va.x & 0xffff));
        a1 += bf2f((ushort)(va.x >> 16));
        a2 += bf2f((ushort)(va.y & 0xffff));
        a3 += bf2f((ushort)(va.y >> 16));
    }
    uint2 o;
    o.x = (unsigned)f2bf(fmaxf(a0, 0.f)) | ((unsigned)f2bf(fmaxf(a1, 0.f)) << 16);
    o.y = (unsigned)f2bf(fmaxf(a2, 0.f)) | ((unsigned)f2bf(fmaxf(a3, 0.f)) << 16);
    ((uint2*)out)[(size_t)node * 64 + lane] = o;
}

// 40-dim final layer: f32 output to d_out
__global__ void agg_relu_40_kernel(const ushort* __restrict__ h, const int* __restrict__ starts,
                                   const int* __restrict__ deg, const int* __restrict__ esrc,
                                   float* __restrict__ out) {
    int wv   = threadIdx.x >> 6;
    int lane = threadIdx.x & 63;
    int node = (blockIdx.x << 2) + wv;
    if (node >= N_NODES) return;
    int s0  = starts[node];
    int cnt = deg[node];
    if (lane < N_CLASSES) {
        float acc = 0.f;
        for (int i = 0; i < cnt; ++i) {
            int s = esrc[s0 + i];
            acc += bf2f(h[(size_t)s * N_CLASSES + lane]);
        }
        out[(size_t)node * N_CLASSES + lane] = fmaxf(acc, 0.f);
    }
}

// ---------------- launch ----------------

extern "C" void kernel_launch(void* const* d_in, const int* in_sizes, int n_in,
                              void* d_out, int out_size, void* d_ws, size_t ws_size,
                              hipStream_t stream) {
    const float* X     = (const float*)d_in[0];
    const int*   edges = (const int*)d_in[1];
    const float* W1 = (const float*)d_in[2];
    const float* b1 = (const float*)d_in[3];
    const float* W2 = (const float*)d_in[4];
    const float* b2 = (const float*)d_in[5];
    const float* W3 = (const float*)d_in[6];
    const float* b3 = (const float*)d_in[7];
    float* out = (float*)d_out;

    char* ws = (char*)d_ws;
    ushort* Xb   = (ushort*)(ws);                    //  5,120,000 B
    ushort* bufH = (ushort*)(ws + 5120000);          //  5,120,000 B (h per layer)
    ushort* bufY = (ushort*)(ws + 10240000);         //  5,120,000 B (agg out / next A)
    ushort* W1b  = (ushort*)(ws + 15360000);         //    131,072 B (256x256, n-major)
    ushort* W2b  = (ushort*)(ws + 15491072);         //    131,072 B
    ushort* W3b  = (ushort*)(ws + 15622144);         //     20,480 B (40x256, n-major)
    int*   deg    = (int*)(ws + 15642624);           //     40,000 B
    int*   cursor = (int*)(ws + 15682624);           //     40,000 B
    int*   starts = (int*)(ws + 15722624);           //     40,000 B
    int*   esrc   = (int*)(ws + 15762624);           //  1,280,000 B

    const int* srcp = edges;
    const int* dstp = edges + N_EDGES;

    hipMemsetAsync(deg, 0, 80000, stream);  // deg + cursor contiguous

    hist_kernel<<<(N_EDGES + 255) / 256, 256, 0, stream>>>(dstp, deg);
    scan_kernel<<<1, 256, 0, stream>>>(deg, starts);
    place_kernel<<<(N_EDGES + 255) / 256, 256, 0, stream>>>(srcp, dstp, starts, cursor, esrc);

    conv_x_kernel<<<(N_NODES * D_HID / 4 + 255) / 256, 256, 0, stream>>>(X, Xb);
    conv_w_kernel<<<(141312 + 255) / 256, 256, 0, stream>>>(W1, W2, W3, W1b, W2b, W3b);

    dim3 gridG((N_NODES + 127) / 128, 4);   // 79 x 4 (N=256)
    dim3 gridG3((N_NODES + 127) / 128, 1);  // 79 x 1 (N=40)

    // Layer 1
    gemm_mfma_kernel<<<gridG, 256, 0, stream>>>(Xb, W1b, b1, bufH, N_NODES, D_HID);
    agg_relu_256_kernel<<<(N_NODES + 3) / 4, 256, 0, stream>>>(bufH, starts, deg, esrc, bufY);
    // Layer 2
    gemm_mfma_kernel<<<gridG, 256, 0, stream>>>(bufY, W2b, b2, bufH, N_NODES, D_HID);
    agg_relu_256_kernel<<<(N_NODES + 3) / 4, 256, 0, stream>>>(bufH, starts, deg, esrc, bufY);
    // Layer 3
    gemm_mfma_kernel<<<gridG3, 256, 0, stream>>>(bufY, W3b, b3, bufH, N_NODES, N_CLASSES);
    agg_relu_40_kernel<<<(N_NODES + 3) / 4, 256, 0, stream>>>(bufH, starts, deg, esrc, out);
}